// Round 3
// baseline (71.014 us; speedup 1.0000x reference)
//
#include <hip/hip_runtime.h>
#include <math.h>

#define BB 4
#define RR 1024
#define NN 100
#define NROI (BB * RR)
#define RPB 4                      // 4 ROIs/block, 8 groups: (ROI, GT-half) per 32-lane group
#define NBLK (NROI / RPB)          // 1024 blocks, single residency round

// packed best: high 32 = float bits of IoU (>=0, monotone), low 32 = ~gt_idx
// => max picks highest IoU; on exact tie, smallest gt index (argmax-first semantics).
#define INIT_PACK 0x00000000FFFFFFFFull

// corner i of a rect; sign conv. matches reference lxs=[.5,-.5,-.5,.5], lys=[.5,.5,-.5,-.5]
__device__ __forceinline__ void corner_of(int i, float cx0, float cy0, float dx, float dy,
                                          float c, float s, float& X, float& Y) {
    float sx = (i == 0 || i == 3) ? 0.5f : -0.5f;
    float sy = (i <= 1) ? 0.5f : -0.5f;
    float lx = sx * dx, ly = sy * dy;
    X = cx0 + lx * c - ly * s;
    Y = cy0 + lx * s + ly * c;
}

// R2: wave-autonomous structure -> ONE block barrier total.
//  - Each 32-lane group owns (ROI = g>>1, GT half = g&1, 50 GTs). Lanes load their
//    GT row straight from global (2x float4, coalesced) and keep fields + cos/sin
//    in registers. No LDS staging, no staging barrier.
//  - Cheap reject -> ballot -> __ffs bit-walk over survivors (ascending n preserves
//    argmax-first tie rule). Survivor GT fields are shuffle-broadcast from the lane
//    that tested it: no LDS list, no LDS atomics.
//  - Per-group best lives in a register; lane 0 writes s_best[g] once. LDS = 64 B.
//  - Phase C: 28-thread coalesced copy for rois; float4 pair for gt_of_rois.
//  - Kept: 24-lane exact polygon IoU, branchless pseudo-angle ordering (monotone
//    bijection of atan2 => identical cyclic order => identical area).
__global__ __launch_bounds__(256) void sampling_target_fused(
    const float* __restrict__ rois,   // (B,R,7)
    const int*   __restrict__ labels, // (B,R)
    const float* __restrict__ gts,    // (B,N,8)
    float*       __restrict__ out)
{
    __shared__ unsigned long long s_best[8];

    const int tid  = threadIdx.x;
    const int roi0 = blockIdx.x * RPB;
    const int b    = roi0 >> 10;               // RR = 1024, RPB | 1024 -> no batch straddle
    const int g    = tid >> 5;                 // 8 groups
    const int lane = tid & 31;
    const int half = g & 1;                    // which 32-bit half of the wave ballot
    const int rl   = g >> 1;                   // ROI within block
    const int h    = g & 1;                    // GT half: [h*50, h*50+50)
    const int r    = roi0 + rl;

    // ---- group-uniform ROI params (global reads, L1-broadcast; trig once) ----
    const float* A = &rois[r * 7];
    float ax = A[0], ay = A[1], az = A[2], adx = A[3], ady = A[4], adz = A[5], aang = A[6];
    float acs = cosf(aang), asn = sinf(aang);
    float ra  = 0.5f * sqrtf(adx * adx + ady * ady);
    float azl = az - adz * 0.5f, azh = az + adz * 0.5f;
    float va  = adx * ady * adz;

    unsigned long long best = INIT_PACK;

    for (int r2 = 0; r2 < 2; ++r2) {
        int local = r2 * 32 + lane;            // 0..63 within this group's half
        int n     = h * 50 + local;
        bool valid = (local < 50);

        float4 g0 = make_float4(0.f, 0.f, 0.f, 0.f);
        float4 g1 = make_float4(0.f, 0.f, 0.f, 0.f);
        if (valid) {
            const float4* G = (const float4*)&gts[(b * NN + n) * 8];  // 32B row, 16B aligned
            g0 = G[0];
            g1 = G[1];
        }
        float gc = cosf(g1.z), gs = sinf(g1.z);        // safe on zeros for invalid lanes

        // cheap reject (z-overlap + enclosing circles)
        float ohz = fminf(azh, g0.z + g1.y * 0.5f) - fmaxf(azl, g0.z - g1.y * 0.5f);
        float dxc = ax - g0.x, dyc = ay - g0.y;
        float rsum = ra + 0.5f * sqrtf(g0.w * g0.w + g1.x * g1.x);
        bool hit = valid && (ohz > 0.0f) && (dxc * dxc + dyc * dyc <= rsum * rsum);

        unsigned long long m = __ballot(hit);
        unsigned gm = (unsigned)(half ? (m >> 32) : (m & 0xFFFFFFFFull));

        while (gm) {                            // group-uniform trip count
            int j = __ffs(gm) - 1;              // ascending n => stable-argmax tie rule
            gm &= gm - 1;

            // broadcast survivor GT fields from the lane that tested it (registers only)
            float gx_ = __shfl(g0.x, j, 32);
            float gy_ = __shfl(g0.y, j, 32);
            float gz_ = __shfl(g0.z, j, 32);
            float gdx = __shfl(g0.w, j, 32);
            float gdy = __shfl(g1.x, j, 32);
            float gdz = __shfl(g1.y, j, 32);
            float bcs = __shfl(gc, j, 32);
            float bsn = __shfl(gs, j, 32);
            int   nj  = h * 50 + r2 * 32 + j;

            // my candidate vertex (lane -> reference slot k, same ordering)
            float ppx = 0.0f, ppy = 0.0f;
            bool val = false;
            if (lane < 4) {                     // corners of A, tested inside B
                corner_of(lane, ax, ay, adx, ady, acs, asn, ppx, ppy);
                float qx = ppx - gx_, qy = ppy - gy_;
                float lx = qx * bcs + qy * bsn;
                float ly = -qx * bsn + qy * bcs;
                val = (fabsf(lx) <= gdx * 0.5f + 1e-5f) && (fabsf(ly) <= gdy * 0.5f + 1e-5f);
            } else if (lane < 8) {              // corners of B, tested inside A
                corner_of(lane - 4, gx_, gy_, gdx, gdy, bcs, bsn, ppx, ppy);
                float qx = ppx - ax, qy = ppy - ay;
                float lx = qx * acs + qy * asn;
                float ly = -qx * asn + qy * acs;
                val = (fabsf(lx) <= adx * 0.5f + 1e-5f) && (fabsf(ly) <= ady * 0.5f + 1e-5f);
            } else if (lane < 24) {             // edge i of A x edge j of B
                int e = lane - 8;
                int ii = e >> 2, jj = e & 3;
                float a1x, a1y, a2x, a2y, b1x, b1y, b2x, b2y;
                corner_of(ii, ax, ay, adx, ady, acs, asn, a1x, a1y);
                corner_of((ii + 1) & 3, ax, ay, adx, ady, acs, asn, a2x, a2y);
                corner_of(jj, gx_, gy_, gdx, gdy, bcs, bsn, b1x, b1y);
                corner_of((jj + 1) & 3, gx_, gy_, gdx, gdy, bcs, bsn, b2x, b2y);
                float d1x = a2x - a1x, d1y = a2y - a1y;
                float d2x = b2x - b1x, d2y = b2y - b1y;
                float denom = d1x * d2y - d1y * d2x;
                float fx = b1x - a1x, fy = b1y - a1y;
                float safe = (fabsf(denom) > 1e-8f) ? denom : 1e-8f;
                float t = (fx * d2y - fy * d2x) / safe;
                float u = (fx * d1y - fy * d1x) / safe;
                ppx = a1x + t * d1x;
                ppy = a1y + t * d1y;
                val = (fabsf(denom) > 1e-8f) && (t >= 0.0f) && (t <= 1.0f) && (u >= 0.0f) && (u <= 1.0f);
            }

            unsigned long long mv = __ballot(val);
            unsigned gv = (unsigned)(half ? (mv >> 32) : (mv & 0xFFFFFFFFull));
            int nv = __popc(gv);

            float inter_bev = 0.0f;
            if (nv >= 3) {   // group-uniform branch; width-32 shuffles safe inside
                float sx = val ? ppx : 0.0f;
                float sy = val ? ppy : 0.0f;
#pragma unroll
                for (int off = 16; off; off >>= 1) {
                    sx += __shfl_xor(sx, off, 32);
                    sy += __shfl_xor(sy, off, 32);
                }
                float cx = sx / (float)nv, cy = sy / (float)nv;

                // pseudo-angle: strictly monotone in atan2(dyp,dxp) over (-pi,pi],
                // range (-2,2]. Identical cyclic order => identical shoelace area.
                float dxp = ppx - cx, dyp = ppy - cy;
                float den = fabsf(dxp) + fabsf(dyp);
                float pa = dxp / fmaxf(den, 1e-30f);
                float myAng = val ? copysignf(1.0f - pa, dyp) : 1e9f;

                // successor in (angle, index) order, index-only tracking;
                // ascending jx + strict < reproduces stable-argsort tie rules.
                float sAng = 1e30f; int sIdx = 0; bool found = false;
                float gAng = 1e30f; int gIdx = 0;
#pragma unroll
                for (int jx = 0; jx < 24; jx++) {
                    float aj = __shfl(myAng, jx, 32);
                    if (aj < 1e8f) {   // valid jx only
                        bool greater = (aj > myAng) || (aj == myAng && jx > lane);
                        if (greater && aj < sAng) { sAng = aj; sIdx = jx; found = true; }
                        if (aj < gAng) { gAng = aj; gIdx = jx; }
                    }
                }
                int qi = found ? sIdx : gIdx;
                float qx = __shfl(ppx, qi, 32);
                float qy = __shfl(ppy, qi, 32);
                float contrib = val ? (ppx * qy - qx * ppy) : 0.0f;
#pragma unroll
                for (int off = 16; off; off >>= 1)
                    contrib += __shfl_xor(contrib, off, 32);
                inter_bev = 0.5f * fabsf(contrib);
            }

            // IoU (all lanes compute; only lane 0's best is written out)
            float ohp = fminf(azh, gz_ + gdz * 0.5f) - fmaxf(azl, gz_ - gdz * 0.5f); // >0 by reject
            float inter = inter_bev * ohp;
            float vb = gdx * gdy * gdz;
            float v = inter / fmaxf(va + vb - inter, 1e-6f);
            unsigned long long packed =
                ((unsigned long long)__float_as_uint(v) << 32) | (unsigned)(~(unsigned)nj);
            best = (packed > best) ? packed : best;
        }
    }

    if (lane == 0) s_best[g] = best;
    __syncthreads();                            // the ONLY block barrier

    // ---- Phase C: outputs ----
    float* out_rois = out;                      // NROI*7
    float* out_gor  = out + NROI * 7;           // NROI*8
    float* out_max  = out_gor + NROI * 8;       // NROI
    float* out_lab  = out_max + NROI;           // NROI
    float* out_msk  = out_lab + NROI;           // NROI

    if (tid < RPB * 7)                          // coalesced 112B passthrough
        out_rois[roi0 * 7 + tid] = rois[roi0 * 7 + tid];

    if (tid < RPB) {
        unsigned long long p0 = s_best[2 * tid];
        unsigned long long p1 = s_best[2 * tid + 1];
        unsigned long long packed = (p0 > p1) ? p0 : p1;   // cross-half combine, same tie rule
        float mo = __uint_as_float((unsigned)(packed >> 32));
        int besti = (int)(~(unsigned)(packed & 0xFFFFFFFFu)); // no-survivor => 0 (argmax of zeros)

        int rr_ = roi0 + tid;
        const float4* G = (const float4*)&gts[(b * NN + besti) * 8];  // L1-hot
        float4 q0 = G[0];
        float4 q1 = G[1];
        float4* og = (float4*)&out_gor[rr_ * 8];                      // 32B-aligned
        og[0] = q0;
        og[1] = q1;

        out_max[rr_] = mo;
        out_lab[rr_] = (float)labels[rr_];
        out_msk[rr_] = (mo > 0.55f) ? 1.0f : 0.0f;
    }
}

extern "C" void kernel_launch(void* const* d_in, const int* in_sizes, int n_in,
                              void* d_out, int out_size, void* d_ws, size_t ws_size,
                              hipStream_t stream) {
    const float* rois   = (const float*)d_in[0];  // (4,1024,7) f32
    const int*   labels = (const int*)d_in[1];    // (4,1024) i32
    const float* gts    = (const float*)d_in[2];  // (4,100,8) f32
    float* out = (float*)d_out;

    hipLaunchKernelGGL(sampling_target_fused, dim3(NBLK), dim3(256), 0, stream,
                       rois, labels, gts, out);
}

// Round 4
// 69.453 us; speedup vs baseline: 1.0225x; 1.0225x over previous
//
#include <hip/hip_runtime.h>
#include <math.h>

#define BB 4
#define RR 1024
#define NN 100
#define NROI (BB * RR)
#define RPB 4                      // 4 waves/block, wave w <-> ROI roi0+w
#define NBLK (NROI / RPB)          // 1024 blocks, single residency round

// packed best: high 32 = float bits of IoU (>=0, monotone), low 32 = ~gt_idx
// => max picks highest IoU; on exact tie, smallest gt index (argmax-first semantics).
// INIT encodes (IoU=0, gt=0) which matches argmax-of-all-zeros.
#define INIT_PACK 0x00000000FFFFFFFFull

// corner i of a rect; sign conv. matches reference lxs=[.5,-.5,-.5,.5], lys=[.5,.5,-.5,-.5]
__device__ __forceinline__ void corner_of(int i, float cx0, float cy0, float dx, float dy,
                                          float c, float s, float& X, float& Y) {
    float sx = (i == 0 || i == 3) ? 0.5f : -0.5f;
    float sy = (i <= 1) ? 0.5f : -0.5f;
    float lx = sx * dx, ly = sy * dy;
    X = cx0 + lx * c - ly * s;
    Y = cy0 + lx * s + ly * c;
}

// One survivor-walk over ballot mask m (wave-uniform). The wave's two 32-lane
// halves co-process consecutive set bits (lo: bit 2t, hi: bit 2t+1) of the SAME
// ROI's survivor list -> ceil(k/2) wave-uniform rounds (R1-grade balance, no
// divergent loop trip counts). Survivor GT fields broadcast width-64 from the
// lane that prefetched the row. Returns updated packed best (group-uniform).
__device__ __forceinline__ unsigned long long walk_stage(
    unsigned long long m, int nbase,
    float4 g0, float4 g1, float gc, float gs,            // this lane's GT row + trig
    float ax, float ay, float azl, float azh,
    float adx, float ady, float acs, float asn, float va,
    int lane, int half, unsigned long long best)
{
    while (m) {                                          // wave-uniform trip count
        int j0 = __ffsll(m) - 1; m &= m - 1;             // ascending n (tie rule safe anyway)
        int j1 = -1;
        if (m) { j1 = __ffsll(m) - 1; m &= m - 1; }
        int j = half ? j1 : j0;                          // my half's survivor lane
        bool active = (j >= 0);                          // group-uniform
        int js = active ? j : 0;

        // broadcast survivor GT fields (width-64, from prefetching lane)
        float gx_ = __shfl(g0.x, js, 64);
        float gy_ = __shfl(g0.y, js, 64);
        float gz_ = __shfl(g0.z, js, 64);
        float gdx = __shfl(g0.w, js, 64);
        float gdy = __shfl(g1.x, js, 64);
        float gdz = __shfl(g1.y, js, 64);
        float bcs = __shfl(gc, js, 64);
        float bsn = __shfl(gs, js, 64);

        // my candidate vertex (lane -> reference slot k, same ordering)
        float ppx = 0.0f, ppy = 0.0f;
        bool val = false;
        if (lane < 4) {                     // corners of A, tested inside B
            corner_of(lane, ax, ay, adx, ady, acs, asn, ppx, ppy);
            float qx = ppx - gx_, qy = ppy - gy_;
            float lx = qx * bcs + qy * bsn;
            float ly = -qx * bsn + qy * bcs;
            val = (fabsf(lx) <= gdx * 0.5f + 1e-5f) && (fabsf(ly) <= gdy * 0.5f + 1e-5f);
        } else if (lane < 8) {              // corners of B, tested inside A
            corner_of(lane - 4, gx_, gy_, gdx, gdy, bcs, bsn, ppx, ppy);
            float qx = ppx - ax, qy = ppy - ay;
            float lx = qx * acs + qy * asn;
            float ly = -qx * asn + qy * acs;
            val = (fabsf(lx) <= adx * 0.5f + 1e-5f) && (fabsf(ly) <= ady * 0.5f + 1e-5f);
        } else if (lane < 24) {             // edge i of A x edge j of B
            int e = lane - 8;
            int ii = e >> 2, jj = e & 3;
            float a1x, a1y, a2x, a2y, b1x, b1y, b2x, b2y;
            corner_of(ii, ax, ay, adx, ady, acs, asn, a1x, a1y);
            corner_of((ii + 1) & 3, ax, ay, adx, ady, acs, asn, a2x, a2y);
            corner_of(jj, gx_, gy_, gdx, gdy, bcs, bsn, b1x, b1y);
            corner_of((jj + 1) & 3, gx_, gy_, gdx, gdy, bcs, bsn, b2x, b2y);
            float d1x = a2x - a1x, d1y = a2y - a1y;
            float d2x = b2x - b1x, d2y = b2y - b1y;
            float denom = d1x * d2y - d1y * d2x;
            float fx = b1x - a1x, fy = b1y - a1y;
            float safe = (fabsf(denom) > 1e-8f) ? denom : 1e-8f;
            float t = (fx * d2y - fy * d2x) / safe;
            float u = (fx * d1y - fy * d1x) / safe;
            ppx = a1x + t * d1x;
            ppy = a1y + t * d1y;
            val = (fabsf(denom) > 1e-8f) && (t >= 0.0f) && (t <= 1.0f) && (u >= 0.0f) && (u <= 1.0f);
        }
        val = val && active;

        unsigned long long mv = __ballot(val);
        unsigned gv = (unsigned)(half ? (mv >> 32) : (mv & 0xFFFFFFFFull));
        int nv = __popc(gv);

        float inter_bev = 0.0f;
        if (nv >= 3) {   // group-uniform branch; width-32 shuffles stay in-group
            float sx = val ? ppx : 0.0f;
            float sy = val ? ppy : 0.0f;
#pragma unroll
            for (int off = 16; off; off >>= 1) {
                sx += __shfl_xor(sx, off, 32);
                sy += __shfl_xor(sy, off, 32);
            }
            float cx = sx / (float)nv, cy = sy / (float)nv;

            // pseudo-angle: strictly monotone in atan2(dyp,dxp) over (-pi,pi],
            // range (-2,2]. Identical cyclic order => identical shoelace area.
            float dxp = ppx - cx, dyp = ppy - cy;
            float den = fabsf(dxp) + fabsf(dyp);
            float pa = dxp / fmaxf(den, 1e-30f);
            float myAng = val ? copysignf(1.0f - pa, dyp) : 1e9f;

            // successor in (angle, index) order, index-only tracking;
            // ascending jx + strict < reproduces stable-argsort tie rules.
            float sAng = 1e30f; int sIdx = 0; bool found = false;
            float gAng = 1e30f; int gIdx = 0;
#pragma unroll
            for (int jx = 0; jx < 24; jx++) {
                float aj = __shfl(myAng, jx, 32);
                if (aj < 1e8f) {   // valid jx only
                    bool greater = (aj > myAng) || (aj == myAng && jx > lane);
                    if (greater && aj < sAng) { sAng = aj; sIdx = jx; found = true; }
                    if (aj < gAng) { gAng = aj; gIdx = jx; }
                }
            }
            int qi = found ? sIdx : gIdx;
            float qx = __shfl(ppx, qi, 32);
            float qy = __shfl(ppy, qi, 32);
            float contrib = val ? (ppx * qy - qx * ppy) : 0.0f;
#pragma unroll
            for (int off = 16; off; off >>= 1)
                contrib += __shfl_xor(contrib, off, 32);
            inter_bev = 0.5f * fabsf(contrib);
        }

        if (active) {
            float ohp = fminf(azh, gz_ + gdz * 0.5f) - fmaxf(azl, gz_ - gdz * 0.5f); // >0 by reject
            float inter = inter_bev * ohp;
            float vb = gdx * gdy * gdz;
            float v = inter / fmaxf(va + vb - inter, 1e-6f);
            int nj = nbase + j;
            unsigned long long packed =
                ((unsigned long long)__float_as_uint(v) << 32) | (unsigned)(~(unsigned)nj);
            best = (packed > best) ? packed : best;
        }
    }
    return best;
}

// R3: zero-barrier, zero-LDS, one-load-burst structure.
//  - Wave w owns ROI roi0+w entirely: ROI params+trig wave-uniform, hoisted out
//    of every loop; best lives in registers; NO s_best, NO atomics, NO barriers.
//  - Each lane prefetches BOTH of its GT rows (n=lane, n=64+lane) upfront:
//    single load-latency exposure (R1's amortization without the LDS round-trip).
//  - Survivor walk: halves co-process consecutive survivors of the same ROI ->
//    wave-uniform ceil(k/2) rounds (fixes R2's imbalance/divergence).
//  - Polygon core: verbatim the thrice-verified 24-lane scheme.
__global__ __launch_bounds__(256) void sampling_target_fused(
    const float* __restrict__ rois,   // (B,R,7)
    const int*   __restrict__ labels, // (B,R)
    const float* __restrict__ gts,    // (B,N,8)
    float*       __restrict__ out)
{
    const int tid  = threadIdx.x;
    const int w    = tid >> 6;                 // wave = ROI slot
    const int wl   = tid & 63;
    const int lane = tid & 31;
    const int half = (tid >> 5) & 1;
    const int roi0 = blockIdx.x * RPB;
    const int r    = roi0 + w;
    const int b    = roi0 >> 10;               // RR = 1024, RPB | 1024 -> no batch straddle

    float* out_rois = out;                      // NROI*7
    float* out_gor  = out + NROI * 7;           // NROI*8
    float* out_max  = out_gor + NROI * 8;       // NROI
    float* out_lab  = out_max + NROI;           // NROI
    float* out_msk  = out_lab + NROI;           // NROI

    // ---- early independent outputs (hide under the GT load burst) ----
    if (wl < 7) out_rois[r * 7 + wl] = rois[r * 7 + wl];
    if (wl == 7) out_lab[r] = (float)labels[r];

    // ---- ROI params (wave-uniform; trig once, off all loops) ----
    const float* A = &rois[r * 7];
    float ax = A[0], ay = A[1], az = A[2], adx = A[3], ady = A[4], adz = A[5], aang = A[6];
    float acs = cosf(aang), asn = sinf(aang);
    float ra  = 0.5f * sqrtf(adx * adx + ady * ady);
    float azl = az - adz * 0.5f, azh = az + adz * 0.5f;
    float va  = adx * ady * adz;

    // ---- prefetch both GT rows for this lane (one burst) ----
    const int n1 = 64 + wl;
    const bool v1 = (n1 < NN);
    const float4* G0 = (const float4*)&gts[(b * NN + wl) * 8];   // n0 = wl < 100 always
    float4 a0 = G0[0];
    float4 a1 = G0[1];
    float4 c0 = make_float4(0.f, 0.f, 0.f, 0.f);
    float4 c1 = make_float4(0.f, 0.f, 0.f, 0.f);
    if (v1) {
        const float4* G1 = (const float4*)&gts[(b * NN + n1) * 8];
        c0 = G1[0];
        c1 = G1[1];
    }
    float gc0 = cosf(a1.z), gs0 = sinf(a1.z);
    float gc1 = cosf(c1.z), gs1 = sinf(c1.z);    // zeros for invalid lanes: safe

    // ---- cheap reject, both stages ----
    float oh0 = fminf(azh, a0.z + a1.y * 0.5f) - fmaxf(azl, a0.z - a1.y * 0.5f);
    float dx0 = ax - a0.x, dy0 = ay - a0.y;
    float rs0 = ra + 0.5f * sqrtf(a0.w * a0.w + a1.x * a1.x);
    bool hit0 = (oh0 > 0.0f) && (dx0 * dx0 + dy0 * dy0 <= rs0 * rs0);

    float oh1 = fminf(azh, c0.z + c1.y * 0.5f) - fmaxf(azl, c0.z - c1.y * 0.5f);
    float dx1 = ax - c0.x, dy1 = ay - c0.y;
    float rs1 = ra + 0.5f * sqrtf(c0.w * c0.w + c1.x * c1.x);
    bool hit1 = v1 && (oh1 > 0.0f) && (dx1 * dx1 + dy1 * dy1 <= rs1 * rs1);

    unsigned long long m0 = __ballot(hit0);
    unsigned long long m1 = __ballot(hit1);

    // ---- survivor walks (wave-uniform rounds, halves co-process) ----
    unsigned long long best = INIT_PACK;
    best = walk_stage(m0, 0,  a0, a1, gc0, gs0,
                      ax, ay, azl, azh, adx, ady, acs, asn, va, lane, half, best);
    best = walk_stage(m1, 64, c0, c1, gc1, gs1,
                      ax, ay, azl, azh, adx, ady, acs, asn, va, lane, half, best);

    // ---- cross-half combine (two 32-bit width-64 shuffles) ----
    {
        int p = wl ^ 32;
        unsigned bl = (unsigned)best, bh = (unsigned)(best >> 32);
        unsigned ol = (unsigned)__shfl((int)bl, p, 64);
        unsigned oh_ = (unsigned)__shfl((int)bh, p, 64);
        unsigned long long other = ((unsigned long long)oh_ << 32) | ol;
        best = (other > best) ? other : best;
    }

    // ---- outputs (per-wave, no barrier) ----
    if (wl == 0) {
        float mo = __uint_as_float((unsigned)(best >> 32));
        int besti = (int)(~(unsigned)(best & 0xFFFFFFFFu));  // no-survivor => 0 (argmax of zeros)

        const float4* G = (const float4*)&gts[(b * NN + besti) * 8];  // L1-hot
        float4 q0 = G[0];
        float4 q1 = G[1];
        float4* og = (float4*)&out_gor[r * 8];                        // 32B-aligned
        og[0] = q0;
        og[1] = q1;

        out_max[r] = mo;
        out_msk[r] = (mo > 0.55f) ? 1.0f : 0.0f;
    }
}

extern "C" void kernel_launch(void* const* d_in, const int* in_sizes, int n_in,
                              void* d_out, int out_size, void* d_ws, size_t ws_size,
                              hipStream_t stream) {
    const float* rois   = (const float*)d_in[0];  // (4,1024,7) f32
    const int*   labels = (const int*)d_in[1];    // (4,1024) i32
    const float* gts    = (const float*)d_in[2];  // (4,100,8) f32
    float* out = (float*)d_out;

    hipLaunchKernelGGL(sampling_target_fused, dim3(NBLK), dim3(256), 0, stream,
                       rois, labels, gts, out);
}

// Round 5
// 66.368 us; speedup vs baseline: 1.0700x; 1.0465x over previous
//
#include <hip/hip_runtime.h>
#include <math.h>

#define BB 4
#define RR 1024
#define NN 100
#define NROI (BB * RR)
#define RPB 4                      // measured-best grid shape: 1024 blocks, single residency round
#define PPB (RPB * NN)             // 400 pairs per block
#define NBLK (NROI / RPB)          // 1024 blocks
#define SEGCAP 128                 // per-wave survivor segment (64 pairs x 2 iters, exact bound)

// packed best: high 32 = float bits of IoU (>=0, monotone), low 32 = ~gt_idx
// => max picks highest IoU; on exact tie, smallest gt index (argmax-first semantics).
// INIT encodes (IoU=0, gt=0) which matches argmax-of-all-zeros.
#define INIT_PACK 0x00000000FFFFFFFFull

// corner i of a rect; sign conv. matches reference lxs=[.5,-.5,-.5,.5], lys=[.5,.5,-.5,-.5]
__device__ __forceinline__ void corner_of(int i, float cx0, float cy0, float dx, float dy,
                                          float c, float s, float& X, float& Y) {
    float sx = (i == 0 || i == 3) ? 0.5f : -0.5f;
    float sy = (i <= 1) ? 0.5f : -0.5f;
    float lx = sx * dx, ly = sy * dy;
    X = cx0 + lx * c - ly * s;
    Y = cy0 + lx * s + ly * c;
}

// R4 = R1 (measured best, 66.26) minus one barrier:
//  - Stage and Phase A merged into ONE pre-barrier region. Cheap-reject reads its
//    pair straight from global (L1-hot) so it does not depend on the LDS stage;
//    staging stores overlap reject computes.
//  - Compaction: per-wave segments (ballot + prefix -> s_list[w*128+pos]); no
//    s_cnt atomic, so no init-before-atomic race in the merged region.
//  - Staged arrays trimmed to exactly what Phase B reads (8 GT + 8 ROI); Phase C
//    reads the winning gts row from global (L1-hot float4 pair) instead.
//  - rois/labels passthrough issued pre-barrier (independent of everything).
//  - Phase B: R1's 24-lane polygon core verbatim (thrice-verified), LDS broadcast
//    reads, atomicMax into s_best.
__global__ __launch_bounds__(256) void sampling_target_fused(
    const float* __restrict__ rois,   // (B,R,7)
    const int*   __restrict__ labels, // (B,R)
    const float* __restrict__ gts,    // (B,N,8)
    float*       __restrict__ out)
{
    __shared__ float s_gx[NN], s_gy[NN], s_gz[NN], s_gdx[NN], s_gdy[NN], s_gdz[NN],
                     s_gc[NN], s_gs[NN];
    __shared__ float s_rx[RPB], s_ry[RPB], s_rz[RPB], s_rdx[RPB], s_rdy[RPB], s_rdz[RPB],
                     s_rc[RPB], s_rs[RPB];
    __shared__ int   s_list[4 * SEGCAP];
    __shared__ int   s_wcnt[4];
    __shared__ unsigned long long s_best[RPB];

    const int tid  = threadIdx.x;
    const int w    = tid >> 6;                 // wave id (4 waves)
    const int wl   = tid & 63;
    const int roi0 = blockIdx.x * RPB;
    const int b    = roi0 >> 10;               // RR = 1024, RPB | 1024 -> no batch straddle

    float* out_rois = out;                      // NROI*7
    float* out_gor  = out + NROI * 7;           // NROI*8
    float* out_max  = out_gor + NROI * 8;       // NROI
    float* out_lab  = out_max + NROI;           // NROI
    float* out_msk  = out_lab + NROI;           // NROI

    if (tid < RPB) s_best[tid] = INIT_PACK;

    // ---- early independent outputs (overlap with everything below) ----
    if (tid < RPB * 7) out_rois[roi0 * 7 + tid] = rois[roi0 * 7 + tid];
    if (tid >= 28 && tid < 28 + RPB) {
        int rl = tid - 28;
        out_lab[roi0 + rl] = (float)labels[roi0 + rl];
    }

    // ---- merged stage + Phase A (no barrier between them) ----
    int segbase = 0;
    {   // iteration 0: p = tid (0..255)
        const int p  = tid;
        const int rl = p / NN;
        const int n  = p - rl * NN;
        const float4* G = (const float4*)&gts[(b * NN + n) * 8];   // 32B row, 16B aligned
        float4 g0 = G[0];
        float4 g1 = G[1];

        if (tid < NN) {                         // stage GT row tid (== n, rl==0 here)
            s_gx[tid] = g0.x;  s_gy[tid] = g0.y;  s_gz[tid] = g0.z;  s_gdx[tid] = g0.w;
            s_gdy[tid] = g1.x; s_gdz[tid] = g1.y;
            s_gc[tid] = cosf(g1.z);
            s_gs[tid] = sinf(g1.z);
        } else if (tid < NN + RPB) {            // stage ROI row tid-100
            int rr_ = tid - NN;
            const float* Ar = &rois[(roi0 + rr_) * 7];
            s_rx[rr_] = Ar[0]; s_ry[rr_] = Ar[1]; s_rz[rr_] = Ar[2];
            s_rdx[rr_] = Ar[3]; s_rdy[rr_] = Ar[4]; s_rdz[rr_] = Ar[5];
            s_rc[rr_] = cosf(Ar[6]);
            s_rs[rr_] = sinf(Ar[6]);
        }

        const float* A = &rois[(roi0 + rl) * 7];   // L1-hot (112B total)
        float oh = fminf(A[2] + A[5] * 0.5f, g0.z + g1.y * 0.5f)
                 - fmaxf(A[2] - A[5] * 0.5f, g0.z - g1.y * 0.5f);
        float dxc = A[0] - g0.x, dyc = A[1] - g0.y;
        float ra = 0.5f * sqrtf(A[3] * A[3] + A[4] * A[4]);
        float rb = 0.5f * sqrtf(g0.w * g0.w + g1.x * g1.x);
        float rr = ra + rb;
        bool hit = (oh > 0.0f) && (dxc * dxc + dyc * dyc <= rr * rr);

        unsigned long long m = __ballot(hit);
        if (hit) {
            int pos = __popcll(m & ((1ull << wl) - 1ull));
            s_list[w * SEGCAP + pos] = p;
        }
        segbase = __popcll(m);
    }
    {   // iteration 1: p = tid + 256 (only tid < 144 in-bounds)
        const int p  = tid + 256;
        const bool inb = (p < PPB);
        bool hit = false;
        if (inb) {
            const int rl = p / NN;              // 2 or 3
            const int n  = p - rl * NN;
            const float4* G = (const float4*)&gts[(b * NN + n) * 8];
            float4 g0 = G[0];
            float4 g1 = G[1];
            const float* A = &rois[(roi0 + rl) * 7];
            float oh = fminf(A[2] + A[5] * 0.5f, g0.z + g1.y * 0.5f)
                     - fmaxf(A[2] - A[5] * 0.5f, g0.z - g1.y * 0.5f);
            float dxc = A[0] - g0.x, dyc = A[1] - g0.y;
            float ra = 0.5f * sqrtf(A[3] * A[3] + A[4] * A[4]);
            float rb = 0.5f * sqrtf(g0.w * g0.w + g1.x * g1.x);
            float rr = ra + rb;
            hit = (oh > 0.0f) && (dxc * dxc + dyc * dyc <= rr * rr);
        }
        unsigned long long m = __ballot(hit);
        if (hit) {
            int pos = __popcll(m & ((1ull << wl) - 1ull));
            s_list[w * SEGCAP + segbase + pos] = p + 0;   // p already includes +256
        }
        if (wl == 0) s_wcnt[w] = segbase + __popcll(m);
    }
    __syncthreads();                            // barrier 1 (stage + survivor lists ready)

    // ---- Phase B: lane-parallel exact IoU, one survivor per 32-lane group ----
    const int c0 = s_wcnt[0], c1 = s_wcnt[1], c2 = s_wcnt[2], c3 = s_wcnt[3];
    const int p1 = c0, p2 = c0 + c1, p3 = c0 + c1 + c2;
    const int ct = p3 + c3;                     // ~10 expected
    const int g    = tid >> 5;                  // 8 groups
    const int lane = tid & 31;
    const int half = g & 1;

    for (int i = g; i < ct; i += 8) {
        int seg = (i >= p1) + (i >= p2) + (i >= p3);
        int off = (seg == 0) ? 0 : ((seg == 1) ? p1 : ((seg == 2) ? p2 : p3));
        int p = s_list[seg * SEGCAP + (i - off)];
        int rl = p / NN;
        int n  = p - rl * NN;
        // broadcast LDS reads (group-uniform addresses)
        float ax = s_rx[rl], ay = s_ry[rl], az = s_rz[rl];
        float adx = s_rdx[rl], ady = s_rdy[rl], adz = s_rdz[rl];
        float acs = s_rc[rl], asn = s_rs[rl];
        float gx_ = s_gx[n], gy_ = s_gy[n], gz_ = s_gz[n];
        float gdx = s_gdx[n], gdy = s_gdy[n], gdz = s_gdz[n];
        float bcs = s_gc[n], bsn = s_gs[n];

        // my candidate vertex (lane -> reference slot k, same ordering)
        float ppx = 0.0f, ppy = 0.0f;
        bool val = false;
        if (lane < 4) {                        // corners of A, tested inside B
            corner_of(lane, ax, ay, adx, ady, acs, asn, ppx, ppy);
            float qx = ppx - gx_, qy = ppy - gy_;
            float lx = qx * bcs + qy * bsn;
            float ly = -qx * bsn + qy * bcs;
            val = (fabsf(lx) <= gdx * 0.5f + 1e-5f) && (fabsf(ly) <= gdy * 0.5f + 1e-5f);
        } else if (lane < 8) {                 // corners of B, tested inside A
            corner_of(lane - 4, gx_, gy_, gdx, gdy, bcs, bsn, ppx, ppy);
            float qx = ppx - ax, qy = ppy - ay;
            float lx = qx * acs + qy * asn;
            float ly = -qx * asn + qy * acs;
            val = (fabsf(lx) <= adx * 0.5f + 1e-5f) && (fabsf(ly) <= ady * 0.5f + 1e-5f);
        } else if (lane < 24) {                // edge i of A x edge j of B
            int e = lane - 8;
            int ii = e >> 2, jj = e & 3;
            float a1x, a1y, a2x, a2y, b1x, b1y, b2x, b2y;
            corner_of(ii, ax, ay, adx, ady, acs, asn, a1x, a1y);
            corner_of((ii + 1) & 3, ax, ay, adx, ady, acs, asn, a2x, a2y);
            corner_of(jj, gx_, gy_, gdx, gdy, bcs, bsn, b1x, b1y);
            corner_of((jj + 1) & 3, gx_, gy_, gdx, gdy, bcs, bsn, b2x, b2y);
            float d1x = a2x - a1x, d1y = a2y - a1y;
            float d2x = b2x - b1x, d2y = b2y - b1y;
            float denom = d1x * d2y - d1y * d2x;
            float fx = b1x - a1x, fy = b1y - a1y;
            float safe = (fabsf(denom) > 1e-8f) ? denom : 1e-8f;
            float t = (fx * d2y - fy * d2x) / safe;
            float u = (fx * d1y - fy * d1x) / safe;
            ppx = a1x + t * d1x;
            ppy = a1y + t * d1y;
            val = (fabsf(denom) > 1e-8f) && (t >= 0.0f) && (t <= 1.0f) && (u >= 0.0f) && (u <= 1.0f);
        }

        unsigned long long m = __ballot(val);
        unsigned gm = (unsigned)(half ? (m >> 32) : (m & 0xFFFFFFFFull));
        int nv = __popc(gm);

        float inter_bev = 0.0f;
        if (nv >= 3) {   // group-uniform branch; width-32 shuffles safe inside
            float sx = val ? ppx : 0.0f;
            float sy = val ? ppy : 0.0f;
#pragma unroll
            for (int off2 = 16; off2; off2 >>= 1) {
                sx += __shfl_xor(sx, off2, 32);
                sy += __shfl_xor(sy, off2, 32);
            }
            float cx = sx / (float)nv, cy = sy / (float)nv;

            // pseudo-angle: strictly monotone in atan2(dyp,dxp) over (-pi,pi],
            // range (-2,2]. Identical cyclic order => identical shoelace area.
            float dxp = ppx - cx, dyp = ppy - cy;
            float den = fabsf(dxp) + fabsf(dyp);
            float pa = dxp / fmaxf(den, 1e-30f);
            float myAng = val ? copysignf(1.0f - pa, dyp) : 1e9f;

            // successor in (angle, index) order, index-only tracking;
            // ascending jx + strict < reproduces stable-argsort tie rules.
            float sAng = 1e30f; int sIdx = 0; bool found = false;
            float gAng = 1e30f; int gIdx = 0;
#pragma unroll
            for (int jx = 0; jx < 24; jx++) {
                float aj = __shfl(myAng, jx, 32);
                if (aj < 1e8f) {   // valid jx only
                    bool greater = (aj > myAng) || (aj == myAng && jx > lane);
                    if (greater && aj < sAng) { sAng = aj; sIdx = jx; found = true; }
                    if (aj < gAng) { gAng = aj; gIdx = jx; }
                }
            }
            int qi = found ? sIdx : gIdx;
            float qx = __shfl(ppx, qi, 32);
            float qy = __shfl(ppy, qi, 32);
            float contrib = val ? (ppx * qy - qx * ppy) : 0.0f;
#pragma unroll
            for (int off2 = 16; off2; off2 >>= 1)
                contrib += __shfl_xor(contrib, off2, 32);
            inter_bev = 0.5f * fabsf(contrib);
        }

        if (lane == 0) {
            float oh = fminf(az + adz * 0.5f, gz_ + gdz * 0.5f)
                     - fmaxf(az - adz * 0.5f, gz_ - gdz * 0.5f);   // >0 by Phase A
            float inter = inter_bev * oh;
            float va = adx * ady * adz;
            float vb = gdx * gdy * gdz;
            float v = inter / fmaxf(va + vb - inter, 1e-6f);
            unsigned long long packed =
                ((unsigned long long)__float_as_uint(v) << 32) | (unsigned)(~(unsigned)n);
            atomicMax(&s_best[rl], packed);
        }
    }
    __syncthreads();                            // barrier 2 (s_best ready)

    // ---- Phase C: best-dependent outputs ----
    if (tid < RPB) {
        int r = roi0 + tid;
        unsigned long long packed = s_best[tid];
        float mo = __uint_as_float((unsigned)(packed >> 32));
        int besti = (int)(~(unsigned)(packed & 0xFFFFFFFFu));   // no-survivor => 0

        const float4* G = (const float4*)&gts[(b * NN + besti) * 8];  // L1-hot
        float4 q0 = G[0];
        float4 q1 = G[1];
        float4* og = (float4*)&out_gor[r * 8];                        // 32B-aligned
        og[0] = q0;
        og[1] = q1;

        out_max[r] = mo;
        out_msk[r] = (mo > 0.55f) ? 1.0f : 0.0f;
    }
}

extern "C" void kernel_launch(void* const* d_in, const int* in_sizes, int n_in,
                              void* d_out, int out_size, void* d_ws, size_t ws_size,
                              hipStream_t stream) {
    const float* rois   = (const float*)d_in[0];  // (4,1024,7) f32
    const int*   labels = (const int*)d_in[1];    // (4,1024) i32
    const float* gts    = (const float*)d_in[2];  // (4,100,8) f32
    float* out = (float*)d_out;

    hipLaunchKernelGGL(sampling_target_fused, dim3(NBLK), dim3(256), 0, stream,
                       rois, labels, gts, out);
}